// Round 10
// baseline (73197.064 us; speedup 1.0000x reference)
//
#include <hip/hip_runtime.h>
#include <cstdint>
#include <cstddef>

#define TT 512

// ---- ws layout (float offsets) ----  total 5456896 floats = 21.8 MB
#define O_BAR   0                           // 1024 barrier words (zeroed by prep)
#define O_HT    1024                        // [3 layer][2 parity][512 u][64 m] h^T
#define WS_ZERO (O_HT + 6*32768)            // prep zeroes [0, WS_ZERO)
#define O_CWP0  WS_ZERO                     // [256 p][512 k][8 j]   U0 packed
#define O_CWP1  (O_CWP0 + 256*512*8)        // [256 p][1024 k][8 j]  [W1;U1] packed
#define O_CWP2  (O_CWP1 + 256*1024*8)       // [256 p][1024 k][8 j]  [W2;U2] packed
#define O_W0P   (O_CWP2 + 256*1024*8)       // [256 p][8 e][8 j]     W0 packed
#define WS_ALL  (O_W0P + 256*64)

// barrier word indices (distinct cachelines)
#define BARR(g) (64 + (g) * 16)
#define BGRP    32
#define BREL(g) (512 + (g) * 16)

// Two-level grid barrier over 256 blocks (16 groups x 16). Counters ZEROED by
// prep kernel (mod-16 protocol requires it -- 0xAA poison broke rounds 2-4).
// All probes are atomic RMWs (coherence point); plain loads can serve a stale
// per-XCD L2 line forever. Timeout converts any liveness failure into a
// terminating, recognizable wrong answer instead of a 600s hang.
__device__ __forceinline__ void grid_barrier(unsigned* bar, unsigned target, int tid, int bid) {
  __syncthreads();
  __threadfence();          // release: drain + L2 writeback (agent scope)
  if (tid == 0) {
    const unsigned g = (unsigned)bid & 15u;
    const unsigned o = atomicAdd(&bar[BARR(g)], 1u);
    if ((o & 15u) == 15u) {                        // last of this 16-block group
      const unsigned o2 = atomicAdd(&bar[BGRP], 1u);
      if ((o2 & 15u) == 15u) {                     // last group: release all
#pragma unroll
        for (int q = 0; q < 16; ++q) atomicExch(&bar[BREL(q)], target);
      }
    }
    unsigned spins = 0;
    while (atomicAdd(&bar[BREL(g)], 0u) != target) {   // coherent probe
      if (++spins > 8000u) break;                      // ~3 ms safety net
      __builtin_amdgcn_s_sleep(8);
    }
  }
  __syncthreads();
  __threadfence();          // acquire: invalidate stale cache lines (h)
}

// One LSTM layer phase. Block owns unit pair p => 8 gate cols j=g*2+uu.
// 8 waves k-split K into eighths. h^T reads coalesced (lane=batch row m);
// weights from LDS via wave-uniform broadcast ds_read_b128 (L2-inv immune).
// Accuracy: 32-term f32 fma chains, f64 accumulation across 32-k groups.
__device__ __forceinline__ void lstm_phase(
    int l0flag, int Ktot, const float* __restrict__ wsec,
    const float* __restrict__ belowT, const float* __restrict__ ownT,
    const float* __restrict__ bias, float* __restrict__ hdstT, float* creg,
    const int* __restrict__ tokens, const float* __restrict__ emb,
    const float* __restrict__ w0l, int t,
    double* dz, int p, int tid)
{
  const int lane = tid & 63;                                  // batch row m
  const int w = __builtin_amdgcn_readfirstlane(tid >> 6);     // wave 0..7 -> SGPR
  const int Kq = Ktot >> 3;
  const int k0 = w * Kq;
  const float* hsrc = (Ktot == 512 || w < 4) ? belowT : ownT; // wave-uniform
  const int kbase = (Ktot == 512 || w < 4) ? k0 : k0 - 512;
  const float* wp = wsec + k0 * 8;                            // LDS, uniform addr
  double d[8] = {0.0, 0.0, 0.0, 0.0, 0.0, 0.0, 0.0, 0.0};

  for (int kb = 0; kb < Kq; kb += 32) {
    float s8[8] = {0.f, 0.f, 0.f, 0.f, 0.f, 0.f, 0.f, 0.f};
#pragma unroll
    for (int kk = 0; kk < 32; ++kk) {
      const float xk = hsrc[(kbase + kb + kk) * 64 + lane];   // coalesced 256B
      const float4 wa = *(const float4*)&wp[(kb + kk) * 8];   // LDS broadcast
      const float4 wb = *(const float4*)&wp[(kb + kk) * 8 + 4];
      s8[0] = fmaf(xk, wa.x, s8[0]); s8[1] = fmaf(xk, wa.y, s8[1]);
      s8[2] = fmaf(xk, wa.z, s8[2]); s8[3] = fmaf(xk, wa.w, s8[3]);
      s8[4] = fmaf(xk, wb.x, s8[4]); s8[5] = fmaf(xk, wb.y, s8[5]);
      s8[6] = fmaf(xk, wb.z, s8[6]); s8[7] = fmaf(xk, wb.w, s8[7]);
    }
#pragma unroll
    for (int j = 0; j < 8; ++j) d[j] += (double)s8[j];        // per-32k f64 flush
  }

  if (l0flag && w == 0) {                  // embedding K=8 part (once, wave 0)
    const int tok = tokens[lane * TT + t];
    float s8[8] = {0.f, 0.f, 0.f, 0.f, 0.f, 0.f, 0.f, 0.f};
#pragma unroll
    for (int e = 0; e < 8; ++e) {
      const float xe = emb[tok * 8 + e];
      const float4 wa = *(const float4*)&w0l[e * 8];
      const float4 wb = *(const float4*)&w0l[e * 8 + 4];
      s8[0] = fmaf(xe, wa.x, s8[0]); s8[1] = fmaf(xe, wa.y, s8[1]);
      s8[2] = fmaf(xe, wa.z, s8[2]); s8[3] = fmaf(xe, wa.w, s8[3]);
      s8[4] = fmaf(xe, wb.x, s8[4]); s8[5] = fmaf(xe, wb.y, s8[5]);
      s8[6] = fmaf(xe, wb.z, s8[6]); s8[7] = fmaf(xe, wb.w, s8[7]);
    }
#pragma unroll
    for (int j = 0; j < 8; ++j) d[j] += (double)s8[j];
  }

#pragma unroll
  for (int j = 0; j < 8; ++j) dz[tid * 8 + j] = d[j];
  __syncthreads();

  if (tid < 128) {
    const int m = tid & 63, uu = tid >> 6;
    const int u = 2 * p + uu;
    float zf[4];
#pragma unroll
    for (int g = 0; g < 4; ++g) {
      double zs = (double)bias[(g << 9) + u];
#pragma unroll
      for (int w8 = 0; w8 < 8; ++w8) zs += dz[(w8 * 64 + m) * 8 + g * 2 + uu];
      zf[g] = (float)zs;
    }
    const float iv = 1.f / (1.f + expf(-zf[0]));
    const float fv = 1.f / (1.f + expf(-zf[1]));
    const float gv = tanhf(zf[2]);
    const float ov = 1.f / (1.f + expf(-zf[3]));
    const float cn = fv * (*creg) + iv * gv;   // c lives in a register
    *creg = cn;
    hdstT[u * 64 + m] = ov * tanhf(cn);        // h^T: coalesced over m
  }
  __syncthreads();                             // dz safe for next phase
}

__global__ void __launch_bounds__(256)
rnn_prep(float* __restrict__ ws,
         const float* __restrict__ W0, const float* __restrict__ U0,
         const float* __restrict__ W1, const float* __restrict__ U1,
         const float* __restrict__ W2, const float* __restrict__ U2)
{
  const int tid = (int)threadIdx.x;
  const int bid = (int)blockIdx.x;
  const int gtid = bid * 256 + tid;
  for (int i = gtid; i < WS_ZERO; i += 768 * 256) ws[i] = 0.f;  // bar + h zeroed

  float* CWP0 = ws + O_CWP0;
  float* CWP1 = ws + O_CWP1;
  float* CWP2 = ws + O_CWP2;
  float* W0P  = ws + O_W0P;
  if (bid < 256) {
    const int p = bid;
    for (int k = tid; k < 512; k += 256)
#pragma unroll
      for (int j = 0; j < 8; ++j) {
        const int col = ((j >> 1) << 9) + 2 * p + (j & 1);
        CWP0[((size_t)p * 512 + k) * 8 + j] = U0[(size_t)k * 2048 + col];
      }
    if (tid < 64) {
      const int e = tid >> 3, j = tid & 7;
      const int col = ((j >> 1) << 9) + 2 * p + (j & 1);
      W0P[p * 64 + e * 8 + j] = W0[(size_t)e * 2048 + col];
    }
  } else if (bid < 512) {
    const int p = bid - 256;
    for (int k = tid; k < 1024; k += 256) {
      const float* src = (k < 512) ? &W1[(size_t)k * 2048] : &U1[(size_t)(k - 512) * 2048];
#pragma unroll
      for (int j = 0; j < 8; ++j) {
        const int col = ((j >> 1) << 9) + 2 * p + (j & 1);
        CWP1[((size_t)p * 1024 + k) * 8 + j] = src[col];
      }
    }
  } else {
    const int p = bid - 512;
    for (int k = tid; k < 1024; k += 256) {
      const float* src = (k < 512) ? &W2[(size_t)k * 2048] : &U2[(size_t)(k - 512) * 2048];
#pragma unroll
      for (int j = 0; j < 8; ++j) {
        const int col = ((j >> 1) << 9) + 2 * p + (j & 1);
        CWP2[((size_t)p * 1024 + k) * 8 + j] = src[col];
      }
    }
  }
}

__global__ void __launch_bounds__(512, 1)
rnn_all(const int* __restrict__ tokens, const float* __restrict__ emb,
        const float* __restrict__ b0, const float* __restrict__ b1,
        const float* __restrict__ b2,
        const float* __restrict__ Wd, const float* __restrict__ bd,
        float* __restrict__ out, float* __restrict__ ws)
{
  __shared__ __align__(16) float wl[20544];    // 80.25 KiB weight slice
  __shared__ double dz[4096];                  // 32 KiB partials
  __shared__ float red[512];                   // 2 KiB softmax reduce
  const int tid = (int)threadIdx.x;
  const int p = (int)blockIdx.x;               // unit pair
  unsigned* bar = (unsigned*)ws;
  float* ht = ws + O_HT;

  { // one-time LDS weight load (then immune to per-superstep L2 invalidation)
    const float* s0 = ws + O_CWP0 + (size_t)p * 4096;
    for (int i = tid; i < 4096; i += 512) wl[i] = s0[i];
    const float* s1 = ws + O_CWP1 + (size_t)p * 8192;
    for (int i = tid; i < 8192; i += 512) wl[4096 + i] = s1[i];
    const float* s2 = ws + O_CWP2 + (size_t)p * 8192;
    for (int i = tid; i < 8192; i += 512) wl[12288 + i] = s2[i];
    if (tid < 64) wl[20480 + tid] = ws[O_W0P + p * 64 + tid];
  }
  float c0 = 0.f, c1 = 0.f, c2 = 0.f;          // cell state in registers
  __syncthreads();

  for (int s = 0; s < 515; ++s) {
    const int po = (s + 1) & 1;                // parity of prev-superstep outputs
    const int pw = s & 1;                      // parity written this superstep
    float* h0po = ht + (size_t)(0 * 2 + po) * 32768;
    float* h1po = ht + (size_t)(1 * 2 + po) * 32768;
    float* h2po = ht + (size_t)(2 * 2 + po) * 32768;
    float* h0pw = ht + (size_t)(0 * 2 + pw) * 32768;
    float* h1pw = ht + (size_t)(1 * 2 + pw) * 32768;
    float* h2pw = ht + (size_t)(2 * 2 + pw) * 32768;

    if (s < 512)                               // L0: t=s (K=512 recurrent + emb)
      lstm_phase(1, 512, wl, h0po, h0po, b0, h0pw, &c0, tokens, emb,
                 wl + 20480, s, dz, p, tid);
    if (s >= 1 && s < 513)                     // L1: t=s-1
      lstm_phase(0, 1024, wl + 4096, h0po, h1po, b1, h1pw, &c1,
                 nullptr, nullptr, nullptr, 0, dz, p, tid);
    if (s >= 2 && s < 514)                     // L2: t=s-2
      lstm_phase(0, 1024, wl + 12288, h1po, h2po, b2, h2pw, &c2,
                 nullptr, nullptr, nullptr, 0, dz, p, tid);

    if (s >= 3 && p < 64) {                    // FIN: logits+softmax, t=s-3, row p
      const int r = p;
      const int col = tid & 127, kq = tid >> 7;
      double acc = 0.0;
      for (int kb = 0; kb < 128; kb += 32) {
        float sa = 0.f;
#pragma unroll
        for (int kk = 0; kk < 32; ++kk) {
          const int k = kq * 128 + kb + kk;
          sa = fmaf(h2po[(size_t)k * 64 + r],          // uniform -> broadcast
                    Wd[(size_t)k * 128 + col], sa);    // coalesced
        }
        acc += (double)sa;
      }
      dz[tid] = acc;
      __syncthreads();
      float xlg = -3.0e38f;
      if (tid < 128)
        xlg = (float)(dz[tid] + dz[tid + 128] + dz[tid + 256] + dz[tid + 384]
                      + (double)bd[col]);
      red[tid] = xlg;                       __syncthreads();
      if (tid < 256) red[tid] = fmaxf(red[tid], red[tid + 256]); __syncthreads();
      if (tid < 128) red[tid] = fmaxf(red[tid], red[tid + 128]); __syncthreads();
      if (tid < 64)  red[tid] = fmaxf(red[tid], red[tid + 64]);  __syncthreads();
      if (tid < 32)  red[tid] = fmaxf(red[tid], red[tid + 32]);  __syncthreads();
      if (tid < 16)  red[tid] = fmaxf(red[tid], red[tid + 16]);  __syncthreads();
      if (tid < 8)   red[tid] = fmaxf(red[tid], red[tid + 8]);   __syncthreads();
      if (tid < 4)   red[tid] = fmaxf(red[tid], red[tid + 4]);   __syncthreads();
      if (tid < 2)   red[tid] = fmaxf(red[tid], red[tid + 2]);   __syncthreads();
      if (tid < 1)   red[tid] = fmaxf(red[tid], red[tid + 1]);   __syncthreads();
      const float mx = red[0];              __syncthreads();
      const float ex = (tid < 128) ? expf(xlg - mx) : 0.f;
      red[tid] = ex;                        __syncthreads();
      if (tid < 256) red[tid] += red[tid + 256]; __syncthreads();
      if (tid < 128) red[tid] += red[tid + 128]; __syncthreads();
      if (tid < 64)  red[tid] += red[tid + 64];  __syncthreads();
      if (tid < 32)  red[tid] += red[tid + 32];  __syncthreads();
      if (tid < 16)  red[tid] += red[tid + 16];  __syncthreads();
      if (tid < 8)   red[tid] += red[tid + 8];   __syncthreads();
      if (tid < 4)   red[tid] += red[tid + 4];   __syncthreads();
      if (tid < 2)   red[tid] += red[tid + 2];   __syncthreads();
      if (tid < 1)   red[tid] += red[tid + 1];   __syncthreads();
      const float inv = 1.f / red[0];
      if (tid < 128) out[((size_t)r * 512 + (s - 3)) * 128 + tid] = ex * inv;
    }

    grid_barrier(bar, (unsigned)(s + 1), tid, p);
  }
}

extern "C" void kernel_launch(void* const* d_in, const int* in_sizes, int n_in,
                              void* d_out, int out_size, void* d_ws, size_t ws_size,
                              hipStream_t stream) {
  (void)in_sizes; (void)n_in; (void)out_size;
  if (ws_size < (size_t)WS_ALL * 4) return;    // 21.8 MB, proven available
  const int*   tokens = (const int*)d_in[0];
  const float* emb = (const float*)d_in[1];
  const float* W0 = (const float*)d_in[2];
  const float* U0 = (const float*)d_in[3];
  const float* b0 = (const float*)d_in[4];
  const float* W1 = (const float*)d_in[5];
  const float* U1 = (const float*)d_in[6];
  const float* b1 = (const float*)d_in[7];
  const float* W2 = (const float*)d_in[8];
  const float* U2 = (const float*)d_in[9];
  const float* b2 = (const float*)d_in[10];
  const float* Wd = (const float*)d_in[11];
  const float* bd = (const float*)d_in[12];
  float* out = (float*)d_out;
  float* ws  = (float*)d_ws;

  hipLaunchKernelGGL(rnn_prep, dim3(768), dim3(256), 0, stream,
                     ws, W0, U0, W1, U1, W2, U2);
  hipLaunchKernelGGL(rnn_all, dim3(256), dim3(512), 0, stream,
                     tokens, emb, b0, b1, b2, Wd, bd, out, ws);
}

// Round 11
// 49307.388 us; speedup vs baseline: 1.4845x; 1.4845x over previous
//
#include <hip/hip_runtime.h>
#include <cstdint>
#include <cstddef>

#define TT 512

// ---- ws layout (float offsets) ----  total 5456896 floats = 21.8 MB
#define O_BAR   0                           // 1024 barrier words (zeroed by prep)
#define O_HT    1024                        // [3 layer][2 parity][512 k][64 m] h^T
#define WS_ZERO (O_HT + 6*32768)            // prep zeroes [0, WS_ZERO)
#define O_CWP0  WS_ZERO                     // [256 p][512 k][8 j]   U0 packed
#define O_CWP1  (O_CWP0 + 256*512*8)        // [256 p][1024 k][8 j]  [W1;U1] packed
#define O_CWP2  (O_CWP1 + 256*1024*8)       // [256 p][1024 k][8 j]  [W2;U2] packed
#define O_W0P   (O_CWP2 + 256*1024*8)       // [256 p][8 e][8 j]     W0 packed
#define WS_ALL  (O_W0P + 256*64)

// barrier word indices (distinct cachelines)
#define BARR(g) (64 + (g) * 16)
#define BGRP    32
#define BREL(g) (512 + (g) * 16)

#define DZP 166                             // dz row stride (doubles); 64*166*8=85KB
                                            // >80KB LDS also forces 1 block/CU

// Coherent-point element access for cross-XCD h exchange: relaxed agent-scope
// atomics compile to single global_load/store with sc0+sc1 (bypass stale
// L1/L2, no cache-flush fences). This replaces round 10's __threadfence()
// pair whose L2 writeback-invalidate was the 200us/step disaster (VALUBusy
// 7.3%, FETCH 1.5MB/step refetch).
__device__ __forceinline__ float hload(const float* p) {
  return __hip_atomic_load(p, __ATOMIC_RELAXED, __HIP_MEMORY_SCOPE_AGENT);
}
__device__ __forceinline__ void hstore(float* p, float v) {
  __hip_atomic_store(p, v, __ATOMIC_RELAXED, __HIP_MEMORY_SCOPE_AGENT);
}

// Two-level grid barrier over 256 blocks (16 groups x 16). Counters zeroed by
// prep. All probes are atomic RMWs (coherence point). NO threadfence: h goes
// through sc0sc1 stores (drained by per-wave vmcnt(0) at s_barrier entry),
// so no L2 writeback/invalidate is needed.
__device__ __forceinline__ void grid_barrier(unsigned* bar, unsigned target, int tid, int bid) {
  __syncthreads();          // all waves: compiler emits s_waitcnt vmcnt(0) before s_barrier
  if (tid == 0) {
    asm volatile("s_waitcnt vmcnt(0)" ::: "memory");   // belt & braces for wave 0
    const unsigned g = (unsigned)bid & 15u;
    const unsigned o = atomicAdd(&bar[BARR(g)], 1u);
    if ((o & 15u) == 15u) {                        // last of this 16-block group
      const unsigned o2 = atomicAdd(&bar[BGRP], 1u);
      if ((o2 & 15u) == 15u) {                     // last group: release all
#pragma unroll
        for (int q = 0; q < 16; ++q) atomicExch(&bar[BREL(q)], target);
      }
    }
    unsigned spins = 0;
    while (atomicAdd(&bar[BREL(g)], 0u) != target) {   // coherent probe
      if (++spins > 30000u) break;                     // safety net
      __builtin_amdgcn_s_sleep(4);
    }
  }
  __syncthreads();
}

// One LSTM layer phase. Block owns unit pair p => 8 gate cols j=g*2+uu.
// 8 waves k-split K into eighths. h^T loads: coherent sc0sc1, coalesced over
// lane=m. Weights: NORMAL cached wave-uniform float4 global loads (one 16B
// L2 request per wave; L2 stays warm -- persistent kernel, no flushes).
// Accuracy: 32-term f32 fma chains, f64 accumulation across 32-k groups
// (identical summation order to rounds 5-10: absmax 6.1e-5).
__device__ __forceinline__ void lstm_phase(
    int l0flag, int Ktot, const float* __restrict__ wp0,
    const float* belowT, const float* ownT,
    const float* __restrict__ bias, float* hdstT, float* creg,
    const int* __restrict__ tokens, const float* __restrict__ emb,
    const float* __restrict__ w0p, int t,
    double* dz, int p, int tid)
{
  const int lane = tid & 63;                                  // batch row m
  const int w = __builtin_amdgcn_readfirstlane(tid >> 6);     // wave 0..7 -> SGPR
  const int Kq = Ktot >> 3;
  const int k0 = w * Kq;
  const float* hsrc = (Ktot == 512 || w < 4) ? belowT : ownT; // wave-uniform
  const int kbase = (Ktot == 512 || w < 4) ? k0 : k0 - 512;
  const float* wp = wp0 + (size_t)k0 * 8;                     // sequential stream
  double d[8] = {0.0, 0.0, 0.0, 0.0, 0.0, 0.0, 0.0, 0.0};

  for (int kb = 0; kb < Kq; kb += 32) {
    float s8[8] = {0.f, 0.f, 0.f, 0.f, 0.f, 0.f, 0.f, 0.f};
#pragma unroll
    for (int kk = 0; kk < 32; ++kk) {
      const float xk = hload(&hsrc[(kbase + kb + kk) * 64 + lane]); // coalesced
      const float4 wa = *(const float4*)&wp[(kb + kk) * 8];         // uniform, L2
      const float4 wb = *(const float4*)&wp[(kb + kk) * 8 + 4];
      s8[0] = fmaf(xk, wa.x, s8[0]); s8[1] = fmaf(xk, wa.y, s8[1]);
      s8[2] = fmaf(xk, wa.z, s8[2]); s8[3] = fmaf(xk, wa.w, s8[3]);
      s8[4] = fmaf(xk, wb.x, s8[4]); s8[5] = fmaf(xk, wb.y, s8[5]);
      s8[6] = fmaf(xk, wb.z, s8[6]); s8[7] = fmaf(xk, wb.w, s8[7]);
    }
#pragma unroll
    for (int j = 0; j < 8; ++j) d[j] += (double)s8[j];        // per-32k f64 flush
  }

  if (l0flag && w == 0) {                  // embedding K=8 part (once, wave 0)
    const int tok = tokens[lane * TT + t];
    float s8[8] = {0.f, 0.f, 0.f, 0.f, 0.f, 0.f, 0.f, 0.f};
#pragma unroll
    for (int e = 0; e < 8; ++e) {
      const float xe = emb[tok * 8 + e];
      const float4 wa = *(const float4*)&w0p[e * 8];
      const float4 wb = *(const float4*)&w0p[e * 8 + 4];
      s8[0] = fmaf(xe, wa.x, s8[0]); s8[1] = fmaf(xe, wa.y, s8[1]);
      s8[2] = fmaf(xe, wa.z, s8[2]); s8[3] = fmaf(xe, wa.w, s8[3]);
      s8[4] = fmaf(xe, wb.x, s8[4]); s8[5] = fmaf(xe, wb.y, s8[5]);
      s8[6] = fmaf(xe, wb.z, s8[6]); s8[7] = fmaf(xe, wb.w, s8[7]);
    }
#pragma unroll
    for (int j = 0; j < 8; ++j) d[j] += (double)s8[j];
  }

  // dz[(j*8+w)][m] padded stride: conflict-free b64 (was 32-way at tid*8+j)
#pragma unroll
  for (int j = 0; j < 8; ++j) dz[(size_t)(j * 8 + w) * DZP + lane] = d[j];
  __syncthreads();

  if (tid < 128) {
    const int m = tid & 63, uu = tid >> 6;
    const int u = 2 * p + uu;
    float zf[4];
#pragma unroll
    for (int g = 0; g < 4; ++g) {
      double zs = (double)bias[(g << 9) + u];
#pragma unroll
      for (int w8 = 0; w8 < 8; ++w8)
        zs += dz[(size_t)((g * 2 + uu) * 8 + w8) * DZP + m];
      zf[g] = (float)zs;
    }
    const float iv = 1.f / (1.f + expf(-zf[0]));
    const float fv = 1.f / (1.f + expf(-zf[1]));
    const float gv = tanhf(zf[2]);
    const float ov = 1.f / (1.f + expf(-zf[3]));
    const float cn = fv * (*creg) + iv * gv;   // c lives in a register
    *creg = cn;
    hstore(&hdstT[u * 64 + m], ov * tanhf(cn));    // coherent-point store
  }
  __syncthreads();                             // dz safe for next phase
}

__global__ void __launch_bounds__(256)
rnn_prep(float* __restrict__ ws,
         const float* __restrict__ W0, const float* __restrict__ U0,
         const float* __restrict__ W1, const float* __restrict__ U1,
         const float* __restrict__ W2, const float* __restrict__ U2)
{
  const int tid = (int)threadIdx.x;
  const int bid = (int)blockIdx.x;
  const int gtid = bid * 256 + tid;
  for (int i = gtid; i < WS_ZERO; i += 768 * 256) ws[i] = 0.f;  // bar + h zeroed

  float* CWP0 = ws + O_CWP0;
  float* CWP1 = ws + O_CWP1;
  float* CWP2 = ws + O_CWP2;
  float* W0P  = ws + O_W0P;
  if (bid < 256) {
    const int p = bid;
    for (int k = tid; k < 512; k += 256)
#pragma unroll
      for (int j = 0; j < 8; ++j) {
        const int col = ((j >> 1) << 9) + 2 * p + (j & 1);
        CWP0[((size_t)p * 512 + k) * 8 + j] = U0[(size_t)k * 2048 + col];
      }
    if (tid < 64) {
      const int e = tid >> 3, j = tid & 7;
      const int col = ((j >> 1) << 9) + 2 * p + (j & 1);
      W0P[p * 64 + e * 8 + j] = W0[(size_t)e * 2048 + col];
    }
  } else if (bid < 512) {
    const int p = bid - 256;
    for (int k = tid; k < 1024; k += 256) {
      const float* src = (k < 512) ? &W1[(size_t)k * 2048] : &U1[(size_t)(k - 512) * 2048];
#pragma unroll
      for (int j = 0; j < 8; ++j) {
        const int col = ((j >> 1) << 9) + 2 * p + (j & 1);
        CWP1[((size_t)p * 1024 + k) * 8 + j] = src[col];
      }
    }
  } else {
    const int p = bid - 512;
    for (int k = tid; k < 1024; k += 256) {
      const float* src = (k < 512) ? &W2[(size_t)k * 2048] : &U2[(size_t)(k - 512) * 2048];
#pragma unroll
      for (int j = 0; j < 8; ++j) {
        const int col = ((j >> 1) << 9) + 2 * p + (j & 1);
        CWP2[((size_t)p * 1024 + k) * 8 + j] = src[col];
      }
    }
  }
}

__global__ void __launch_bounds__(512, 1)
rnn_all(const int* __restrict__ tokens, const float* __restrict__ emb,
        const float* __restrict__ b0, const float* __restrict__ b1,
        const float* __restrict__ b2,
        const float* __restrict__ Wd, const float* __restrict__ bd,
        float* __restrict__ out, float* __restrict__ ws)
{
  __shared__ double dz[64 * DZP];              // 85 KiB (also pins 1 block/CU)
  __shared__ float red[512];                   // 2 KiB softmax reduce
  const int tid = (int)threadIdx.x;
  const int p = (int)blockIdx.x;               // unit pair
  unsigned* bar = (unsigned*)ws;
  float* ht = ws + O_HT;
  const float* CWP0 = ws + O_CWP0 + (size_t)p * 512 * 8;
  const float* CWP1 = ws + O_CWP1 + (size_t)p * 1024 * 8;
  const float* CWP2 = ws + O_CWP2 + (size_t)p * 1024 * 8;
  const float* W0P  = ws + O_W0P + p * 64;

  float c0 = 0.f, c1 = 0.f, c2 = 0.f;          // cell state in registers

  for (int s = 0; s < 515; ++s) {
    const int po = (s + 1) & 1;                // parity of prev-superstep outputs
    const int pw = s & 1;                      // parity written this superstep
    float* h0po = ht + (size_t)(0 * 2 + po) * 32768;
    float* h1po = ht + (size_t)(1 * 2 + po) * 32768;
    float* h2po = ht + (size_t)(2 * 2 + po) * 32768;
    float* h0pw = ht + (size_t)(0 * 2 + pw) * 32768;
    float* h1pw = ht + (size_t)(1 * 2 + pw) * 32768;
    float* h2pw = ht + (size_t)(2 * 2 + pw) * 32768;

    if (s < 512)                               // L0: t=s (K=512 recurrent + emb)
      lstm_phase(1, 512, CWP0, h0po, h0po, b0, h0pw, &c0, tokens, emb,
                 W0P, s, dz, p, tid);
    if (s >= 1 && s < 513)                     // L1: t=s-1
      lstm_phase(0, 1024, CWP1, h0po, h1po, b1, h1pw, &c1,
                 nullptr, nullptr, nullptr, 0, dz, p, tid);
    if (s >= 2 && s < 514)                     // L2: t=s-2
      lstm_phase(0, 1024, CWP2, h1po, h2po, b2, h2pw, &c2,
                 nullptr, nullptr, nullptr, 0, dz, p, tid);

    if (s >= 3 && p < 64) {                    // FIN: logits+softmax, t=s-3, row p
      const int r = p;
      const int col = tid & 127, kq = tid >> 7;
      double acc = 0.0;
      for (int kb = 0; kb < 128; kb += 32) {
        float sa = 0.f;
#pragma unroll
        for (int kk = 0; kk < 32; ++kk) {
          const int k = kq * 128 + kb + kk;
          sa = fmaf(hload(&h2po[(size_t)k * 64 + r]),  // coherent, uniform
                    Wd[(size_t)k * 128 + col], sa);    // coalesced, L2-warm
        }
        acc += (double)sa;
      }
      dz[tid] = acc;
      __syncthreads();
      float xlg = -3.0e38f;
      if (tid < 128)
        xlg = (float)(dz[tid] + dz[tid + 128] + dz[tid + 256] + dz[tid + 384]
                      + (double)bd[col]);
      red[tid] = xlg;                       __syncthreads();
      if (tid < 256) red[tid] = fmaxf(red[tid], red[tid + 256]); __syncthreads();
      if (tid < 128) red[tid] = fmaxf(red[tid], red[tid + 128]); __syncthreads();
      if (tid < 64)  red[tid] = fmaxf(red[tid], red[tid + 64]);  __syncthreads();
      if (tid < 32)  red[tid] = fmaxf(red[tid], red[tid + 32]);  __syncthreads();
      if (tid < 16)  red[tid] = fmaxf(red[tid], red[tid + 16]);  __syncthreads();
      if (tid < 8)   red[tid] = fmaxf(red[tid], red[tid + 8]);   __syncthreads();
      if (tid < 4)   red[tid] = fmaxf(red[tid], red[tid + 4]);   __syncthreads();
      if (tid < 2)   red[tid] = fmaxf(red[tid], red[tid + 2]);   __syncthreads();
      if (tid < 1)   red[tid] = fmaxf(red[tid], red[tid + 1]);   __syncthreads();
      const float mx = red[0];              __syncthreads();
      const float ex = (tid < 128) ? expf(xlg - mx) : 0.f;
      red[tid] = ex;                        __syncthreads();
      if (tid < 256) red[tid] += red[tid + 256]; __syncthreads();
      if (tid < 128) red[tid] += red[tid + 128]; __syncthreads();
      if (tid < 64)  red[tid] += red[tid + 64];  __syncthreads();
      if (tid < 32)  red[tid] += red[tid + 32];  __syncthreads();
      if (tid < 16)  red[tid] += red[tid + 16];  __syncthreads();
      if (tid < 8)   red[tid] += red[tid + 8];   __syncthreads();
      if (tid < 4)   red[tid] += red[tid + 4];   __syncthreads();
      if (tid < 2)   red[tid] += red[tid + 2];   __syncthreads();
      if (tid < 1)   red[tid] += red[tid + 1];   __syncthreads();
      const float inv = 1.f / red[0];
      if (tid < 128) out[((size_t)r * 512 + (s - 3)) * 128 + tid] = ex * inv;
    }

    grid_barrier(bar, (unsigned)(s + 1), tid, p);
  }
}

extern "C" void kernel_launch(void* const* d_in, const int* in_sizes, int n_in,
                              void* d_out, int out_size, void* d_ws, size_t ws_size,
                              hipStream_t stream) {
  (void)in_sizes; (void)n_in; (void)out_size;
  if (ws_size < (size_t)WS_ALL * 4) return;    // 21.8 MB, proven available
  const int*   tokens = (const int*)d_in[0];
  const float* emb = (const float*)d_in[1];
  const float* W0 = (const float*)d_in[2];
  const float* U0 = (const float*)d_in[3];
  const float* b0 = (const float*)d_in[4];
  const float* W1 = (const float*)d_in[5];
  const float* U1 = (const float*)d_in[6];
  const float* b1 = (const float*)d_in[7];
  const float* W2 = (const float*)d_in[8];
  const float* U2 = (const float*)d_in[9];
  const float* b2 = (const float*)d_in[10];
  const float* Wd = (const float*)d_in[11];
  const float* bd = (const float*)d_in[12];
  float* out = (float*)d_out;
  float* ws  = (float*)d_ws;

  hipLaunchKernelGGL(rnn_prep, dim3(768), dim3(256), 0, stream,
                     ws, W0, U0, W1, U1, W2, U2);
  hipLaunchKernelGGL(rnn_all, dim3(256), dim3(512), 0, stream,
                     tokens, emb, b0, b1, b2, Wd, bd, out, ws);
}

// Round 12
// 14758.849 us; speedup vs baseline: 4.9595x; 3.3409x over previous
//
#include <hip/hip_runtime.h>
#include <cstdint>
#include <cstddef>

#define TT 512
#define DZP 65                              // dz row stride (doubles), conflict-free

// ---- ws layout (float offsets) ----  total 5456896 floats = 21.8 MB
#define O_BAR   0                           // 1024 barrier words (zeroed by prep)
#define O_HT    1024                        // [3 layer][2 parity] hq[128 kq][64 m][4 q]
#define WS_ZERO (O_HT + 6*32768)            // prep zeroes [0, WS_ZERO)
#define O_CWP0  WS_ZERO                     // [256 p][512 k][8 j]   U0 packed
#define O_CWP1  (O_CWP0 + 256*512*8)        // [256 p][1024 k][8 j]  [W1;U1] packed
#define O_CWP2  (O_CWP1 + 256*1024*8)       // [256 p][1024 k][8 j]  [W2;U2] packed
#define O_W0P   (O_CWP2 + 256*1024*8)       // [256 p][8 e][8 j]     W0 packed
#define WS_ALL  (O_W0P + 256*64)

// barrier word indices (distinct cachelines)
#define BARR(g) (64 + (g) * 16)
#define BGRP    32
#define BREL(g) (512 + (g) * 16)

typedef float f4v __attribute__((ext_vector_type(4)));

// Coherent (cross-XCD) 16B load/4B store: PLAIN global ops with sc0+sc1
// (bypass stale L1/L2, served at the coherence point). Unlike round 11's
// __hip_atomic loads these are batchable: issue N, then one vmcnt wait.
__device__ __forceinline__ void coh_ld16(f4v* dst, const f4v* addr) {
  asm volatile("global_load_dwordx4 %0, %1, off sc0 sc1" : "=v"(*dst) : "v"(addr));
}
__device__ __forceinline__ void coh_st4(float* addr, float v) {
  asm volatile("global_store_dword %0, %1, off sc0 sc1" :: "v"(addr), "v"(v) : "memory");
}
__device__ __forceinline__ void vm_wait0() {
  asm volatile("s_waitcnt vmcnt(0)" ::: "memory");
  __builtin_amdgcn_sched_barrier(0);        // rule #18: pin uses after the wait
}

// Two-level grid barrier over 256 blocks (16 groups x 16). Counters zeroed by
// prep. All probes are atomic RMWs (coherence point). No threadfence (the L2
// writeback-invalidate was round 10's 200us/step); coherent h stores are
// drained by vmcnt(0) before arrival.
__device__ __forceinline__ void grid_barrier(unsigned* bar, unsigned target, int tid, int bid) {
  __syncthreads();
  if (tid == 0) {
    asm volatile("s_waitcnt vmcnt(0)" ::: "memory");
    const unsigned g = (unsigned)bid & 15u;
    const unsigned o = atomicAdd(&bar[BARR(g)], 1u);
    if ((o & 15u) == 15u) {
      const unsigned o2 = atomicAdd(&bar[BGRP], 1u);
      if ((o2 & 15u) == 15u) {
#pragma unroll
        for (int q = 0; q < 16; ++q) atomicExch(&bar[BREL(q)], target);
      }
    }
    unsigned spins = 0;
    while (atomicAdd(&bar[BREL(g)], 0u) != target) {
      if (++spins > 30000u) break;                     // safety net
      __builtin_amdgcn_s_sleep(2);
    }
  }
  __syncthreads();
}

// One LSTM layer phase. Block owns unit pair p => 8 gate cols j. 8 waves
// k-split. h: batched coherent quad loads (16 issued, 1 wait). Weights: LDS
// wave-uniform broadcast reads (conflict-free). Accuracy: 32-term f32 fma
// chains + f64 accumulation -- summation order identical to rounds 5-11.
__device__ __forceinline__ void lstm_phase(
    int l0flag, int Ktot, const float* wsec,
    const float* belowT, const float* ownT,
    const float* __restrict__ bias, float* hdstT, float* creg,
    const int* __restrict__ tokens, const float* __restrict__ emb,
    const float* w0l, int t,
    double* dz, int p, int tid)
{
  const int lane = tid & 63;                                  // batch row m
  const int w = __builtin_amdgcn_readfirstlane(tid >> 6);     // wave 0..7 -> SGPR
  const int Kq = Ktot >> 3;                                   // 64 or 128
  const int k0 = w * Kq;
  const float* hsrc = (Ktot == 512 || w < 4) ? belowT : ownT; // wave-uniform
  const int kbase = (Ktot == 512 || w < 4) ? k0 : k0 - 512;
  const f4v* hq = (const f4v*)hsrc;
  const int nch = Kq >> 6;                                    // 1 or 2 chunks
  double d[8] = {0.0, 0.0, 0.0, 0.0, 0.0, 0.0, 0.0, 0.0};

  for (int ch = 0; ch < nch; ++ch) {
    const int kq0 = (kbase >> 2) + ch * 16;
    f4v h[16];
#pragma unroll
    for (int i = 0; i < 16; ++i)                              // issue 16 loads
      coh_ld16(&h[i], hq + (size_t)(kq0 + i) * 64 + lane);
    vm_wait0();                                               // one wait
#pragma unroll
    for (int g2 = 0; g2 < 2; ++g2) {                          // two 32-k chains
      float s8[8] = {0.f, 0.f, 0.f, 0.f, 0.f, 0.f, 0.f, 0.f};
#pragma unroll
      for (int i = 0; i < 8; ++i) {
        const f4v hv = h[g2 * 8 + i];
#pragma unroll
        for (int q = 0; q < 4; ++q) {
          const float xk = hv[q];
          const int kl = k0 + ch * 64 + g2 * 32 + i * 4 + q;
          const float4 wa = *(const float4*)&wsec[(size_t)kl * 8];     // LDS bcast
          const float4 wb = *(const float4*)&wsec[(size_t)kl * 8 + 4];
          s8[0] = fmaf(xk, wa.x, s8[0]); s8[1] = fmaf(xk, wa.y, s8[1]);
          s8[2] = fmaf(xk, wa.z, s8[2]); s8[3] = fmaf(xk, wa.w, s8[3]);
          s8[4] = fmaf(xk, wb.x, s8[4]); s8[5] = fmaf(xk, wb.y, s8[5]);
          s8[6] = fmaf(xk, wb.z, s8[6]); s8[7] = fmaf(xk, wb.w, s8[7]);
        }
      }
#pragma unroll
      for (int j = 0; j < 8; ++j) d[j] += (double)s8[j];      // per-32k f64 flush
    }
  }

  if (l0flag && w == 0) {                  // embedding K=8 part (once, wave 0)
    const int tok = tokens[lane * TT + t];
    float s8[8] = {0.f, 0.f, 0.f, 0.f, 0.f, 0.f, 0.f, 0.f};
#pragma unroll
    for (int e = 0; e < 8; ++e) {
      const float xe = emb[tok * 8 + e];
      const float4 wa = *(const float4*)&w0l[e * 8];
      const float4 wb = *(const float4*)&w0l[e * 8 + 4];
      s8[0] = fmaf(xe, wa.x, s8[0]); s8[1] = fmaf(xe, wa.y, s8[1]);
      s8[2] = fmaf(xe, wa.z, s8[2]); s8[3] = fmaf(xe, wa.w, s8[3]);
      s8[4] = fmaf(xe, wb.x, s8[4]); s8[5] = fmaf(xe, wb.y, s8[5]);
      s8[6] = fmaf(xe, wb.z, s8[6]); s8[7] = fmaf(xe, wb.w, s8[7]);
    }
#pragma unroll
    for (int j = 0; j < 8; ++j) d[j] += (double)s8[j];
  }

#pragma unroll
  for (int j = 0; j < 8; ++j) dz[(j * 8 + w) * DZP + lane] = d[j];
  __syncthreads();

  if (tid < 128) {
    const int m = tid & 63, uu = tid >> 6;
    const int u = 2 * p + uu;
    float zf[4];
#pragma unroll
    for (int g = 0; g < 4; ++g) {
      double zs = (double)bias[(g << 9) + u];
#pragma unroll
      for (int w8 = 0; w8 < 8; ++w8)
        zs += dz[((g * 2 + uu) * 8 + w8) * DZP + m];
      zf[g] = (float)zs;
    }
    const float iv = 1.f / (1.f + expf(-zf[0]));
    const float fv = 1.f / (1.f + expf(-zf[1]));
    const float gv = tanhf(zf[2]);
    const float ov = 1.f / (1.f + expf(-zf[3]));
    const float cn = fv * (*creg) + iv * gv;       // c lives in a register
    *creg = cn;
    coh_st4(&hdstT[((u >> 2) * 64 + m) * 4 + (u & 3)], ov * tanhf(cn));
  }
  __syncthreads();                                 // dz safe for next phase
}

__global__ void __launch_bounds__(256)
rnn_prep(float* __restrict__ ws,
         const float* __restrict__ W0, const float* __restrict__ U0,
         const float* __restrict__ W1, const float* __restrict__ U1,
         const float* __restrict__ W2, const float* __restrict__ U2)
{
  const int tid = (int)threadIdx.x;
  const int bid = (int)blockIdx.x;
  const int gtid = bid * 256 + tid;
  for (int i = gtid; i < WS_ZERO; i += 768 * 256) ws[i] = 0.f;  // bar + h zeroed

  float* CWP0 = ws + O_CWP0;
  float* CWP1 = ws + O_CWP1;
  float* CWP2 = ws + O_CWP2;
  float* W0P  = ws + O_W0P;
  if (bid < 256) {
    const int p = bid;
    for (int k = tid; k < 512; k += 256)
#pragma unroll
      for (int j = 0; j < 8; ++j) {
        const int col = ((j >> 1) << 9) + 2 * p + (j & 1);
        CWP0[((size_t)p * 512 + k) * 8 + j] = U0[(size_t)k * 2048 + col];
      }
    if (tid < 64) {
      const int e = tid >> 3, j = tid & 7;
      const int col = ((j >> 1) << 9) + 2 * p + (j & 1);
      W0P[p * 64 + e * 8 + j] = W0[(size_t)e * 2048 + col];
    }
  } else if (bid < 512) {
    const int p = bid - 256;
    for (int k = tid; k < 1024; k += 256) {
      const float* src = (k < 512) ? &W1[(size_t)k * 2048] : &U1[(size_t)(k - 512) * 2048];
#pragma unroll
      for (int j = 0; j < 8; ++j) {
        const int col = ((j >> 1) << 9) + 2 * p + (j & 1);
        CWP1[((size_t)p * 1024 + k) * 8 + j] = src[col];
      }
    }
  } else {
    const int p = bid - 512;
    for (int k = tid; k < 1024; k += 256) {
      const float* src = (k < 512) ? &W2[(size_t)k * 2048] : &U2[(size_t)(k - 512) * 2048];
#pragma unroll
      for (int j = 0; j < 8; ++j) {
        const int col = ((j >> 1) << 9) + 2 * p + (j & 1);
        CWP2[((size_t)p * 1024 + k) * 8 + j] = src[col];
      }
    }
  }
}

__global__ void __launch_bounds__(512, 1)
rnn_all(const int* __restrict__ tokens, const float* __restrict__ emb,
        const float* __restrict__ b0, const float* __restrict__ b1,
        const float* __restrict__ b2,
        const float* __restrict__ Wd, const float* __restrict__ bd,
        float* __restrict__ out, float* __restrict__ ws)
{
  __shared__ __align__(16) float wl[20544];    // 80.25 KiB weight slice
  __shared__ double dz[64 * DZP];              // 33.3 KiB partials (padded)
  __shared__ float red[512];                   // 2 KiB softmax reduce
  const int tid = (int)threadIdx.x;
  const int p = (int)blockIdx.x;               // unit pair
  unsigned* bar = (unsigned*)ws;
  float* ht = ws + O_HT;

  { // one-time LDS weight load (broadcast-read thereafter; no refetch ever)
    const float* s0 = ws + O_CWP0 + (size_t)p * 4096;
    for (int i = tid; i < 4096; i += 512) wl[i] = s0[i];
    const float* s1 = ws + O_CWP1 + (size_t)p * 8192;
    for (int i = tid; i < 8192; i += 512) wl[4096 + i] = s1[i];
    const float* s2 = ws + O_CWP2 + (size_t)p * 8192;
    for (int i = tid; i < 8192; i += 512) wl[12288 + i] = s2[i];
    if (tid < 64) wl[20480 + tid] = ws[O_W0P + p * 64 + tid];
  }
  float c0 = 0.f, c1 = 0.f, c2 = 0.f;          // cell state in registers
  __syncthreads();

  for (int s = 0; s < 515; ++s) {
    const int po = (s + 1) & 1;                // parity of prev-superstep outputs
    const int pw = s & 1;                      // parity written this superstep
    float* h0po = ht + (size_t)(0 * 2 + po) * 32768;
    float* h1po = ht + (size_t)(1 * 2 + po) * 32768;
    float* h2po = ht + (size_t)(2 * 2 + po) * 32768;
    float* h0pw = ht + (size_t)(0 * 2 + pw) * 32768;
    float* h1pw = ht + (size_t)(1 * 2 + pw) * 32768;
    float* h2pw = ht + (size_t)(2 * 2 + pw) * 32768;

    if (s < 512)                               // L0: t=s (K=512 recurrent + emb)
      lstm_phase(1, 512, wl, h0po, h0po, b0, h0pw, &c0, tokens, emb,
                 wl + 20480, s, dz, p, tid);
    if (s >= 1 && s < 513)                     // L1: t=s-1
      lstm_phase(0, 1024, wl + 4096, h0po, h1po, b1, h1pw, &c1,
                 nullptr, nullptr, nullptr, 0, dz, p, tid);
    if (s >= 2 && s < 514)                     // L2: t=s-2
      lstm_phase(0, 1024, wl + 12288, h1po, h2po, b2, h2pw, &c2,
                 nullptr, nullptr, nullptr, 0, dz, p, tid);

    if (s >= 3 && p < 64) {                    // FIN: logits+softmax, t=s-3, row p
      const int r = p;
      const f4v* h2q = (const f4v*)h2po;
      const int col = tid & 127, kq4 = tid >> 7;
      double acc = 0.0;
      for (int ch = 0; ch < 4; ++ch) {
        f4v h[8];
#pragma unroll
        for (int i = 0; i < 8; ++i)
          coh_ld16(&h[i], h2q + (size_t)(kq4 * 32 + ch * 8 + i) * 64 + r);
        vm_wait0();
        float sa = 0.f;
#pragma unroll
        for (int i = 0; i < 8; ++i)
#pragma unroll
          for (int q = 0; q < 4; ++q) {
            const int k = (kq4 * 32 + ch * 8 + i) * 4 + q;
            sa = fmaf(h[i][q], Wd[(size_t)k * 128 + col], sa);
          }
        acc += (double)sa;
      }
      dz[tid] = acc;
      __syncthreads();
      float xlg = -3.0e38f;
      if (tid < 128)
        xlg = (float)(dz[tid] + dz[tid + 128] + dz[tid + 256] + dz[tid + 384]
                      + (double)bd[col]);
      red[tid] = xlg;                       __syncthreads();
      if (tid < 256) red[tid] = fmaxf(red[tid], red[tid + 256]); __syncthreads();
      if (tid < 128) red[tid] = fmaxf(red[tid], red[tid + 128]); __syncthreads();
      if (tid < 64)  red[tid] = fmaxf(red[tid], red[tid + 64]);  __syncthreads();
      if (tid < 32)  red[tid] = fmaxf(red[tid], red[tid + 32]);  __syncthreads();
      if (tid < 16)  red[tid] = fmaxf(red[tid], red[tid + 16]);  __syncthreads();
      if (tid < 8)   red[tid] = fmaxf(red[tid], red[tid + 8]);   __syncthreads();
      if (tid < 4)   red[tid] = fmaxf(red[tid], red[tid + 4]);   __syncthreads();
      if (tid < 2)   red[tid] = fmaxf(red[tid], red[tid + 2]);   __syncthreads();
      if (tid < 1)   red[tid] = fmaxf(red[tid], red[tid + 1]);   __syncthreads();
      const float mx = red[0];              __syncthreads();
      const float ex = (tid < 128) ? expf(xlg - mx) : 0.f;
      red[tid] = ex;                        __syncthreads();
      if (tid < 256) red[tid] += red[tid + 256]; __syncthreads();
      if (tid < 128) red[tid] += red[tid + 128]; __syncthreads();
      if (tid < 64)  red[tid] += red[tid + 64];  __syncthreads();
      if (tid < 32)  red[tid] += red[tid + 32];  __syncthreads();
      if (tid < 16)  red[tid] += red[tid + 16];  __syncthreads();
      if (tid < 8)   red[tid] += red[tid + 8];   __syncthreads();
      if (tid < 4)   red[tid] += red[tid + 4];   __syncthreads();
      if (tid < 2)   red[tid] += red[tid + 2];   __syncthreads();
      if (tid < 1)   red[tid] += red[tid + 1];   __syncthreads();
      const float inv = 1.f / red[0];
      if (tid < 128) out[((size_t)r * 512 + (s - 3)) * 128 + tid] = ex * inv;
    }

    grid_barrier(bar, (unsigned)(s + 1), tid, p);
  }
}

extern "C" void kernel_launch(void* const* d_in, const int* in_sizes, int n_in,
                              void* d_out, int out_size, void* d_ws, size_t ws_size,
                              hipStream_t stream) {
  (void)in_sizes; (void)n_in; (void)out_size;
  if (ws_size < (size_t)WS_ALL * 4) return;    // 21.8 MB, proven available
  const int*   tokens = (const int*)d_in[0];
  const float* emb = (const float*)d_in[1];
  const float* W0 = (const float*)d_in[2];
  const float* U0 = (const float*)d_in[3];
  const float* b0 = (const float*)d_in[4];
  const float* W1 = (const float*)d_in[5];
  const float* U1 = (const float*)d_in[6];
  const float* b1 = (const float*)d_in[7];
  const float* W2 = (const float*)d_in[8];
  const float* U2 = (const float*)d_in[9];
  const float* b2 = (const float*)d_in[10];
  const float* Wd = (const float*)d_in[11];
  const float* bd = (const float*)d_in[12];
  float* out = (float*)d_out;
  float* ws  = (float*)d_ws;

  hipLaunchKernelGGL(rnn_prep, dim3(768), dim3(256), 0, stream,
                     ws, W0, U0, W1, U1, W2, U2);
  hipLaunchKernelGGL(rnn_all, dim3(256), dim3(512), 0, stream,
                     tokens, emb, b0, b1, b2, Wd, bd, out, ws);
}